// Round 1
// baseline (897.251 us; speedup 1.0000x reference)
//
#include <hip/hip_runtime.h>

// Light-field linear filter: out[b,s,o,h,w] = clip(sum_{i,k} lf_patch[b,s,i,h,w,k] * W[s,o,i,h,w,k] + bias[s,o,h,w], 0, 1)
// Memory-bound: weights stream = 430 MB dominates. Strategy: LDS-stage the
// contiguous per-(s,o,i,h) weight slice (41.5 KB) coalesced via global_load_lds,
// LDS-stage lf rows (padded, zero-filled borders) per ky-third, compute from LDS.

#define ST 9
#define INC 3
#define OUTC 3
#define OHH 128
#define OWW 128
#define KDIM 9
#define KK 81
#define HH 384
#define WW 384
#define BATCH 4
#define HWSZ (HH*WW)          // 147456
#define WSLICE (OWW*KK)       // 10368 floats per (s,o,i,h)

__device__ __forceinline__ void gll16(const float* g, float* l) {
  __builtin_amdgcn_global_load_lds((const __attribute__((address_space(1))) void*)g,
                                   (__attribute__((address_space(3))) void*)l, 16, 0, 0);
}
__device__ __forceinline__ void gll4(const float* g, float* l) {
  __builtin_amdgcn_global_load_lds((const __attribute__((address_space(1))) void*)g,
                                   (__attribute__((address_space(3))) void*)l, 4, 0, 0);
}

__global__ __launch_bounds__(128) void lf_filter_kernel(
    const float* __restrict__ lf, const float* __restrict__ wts,
    const float* __restrict__ bias, float* __restrict__ out)
{
  __shared__ float ldsW[WSLICE];         // [w][81], 41472 B
  __shared__ float lfb[BATCH][3][400];   // padded rows: data in cols [4,388); pads stay 0

  const int t = threadIdx.x;
  const int s = blockIdx.x >> 7;         // blockIdx.x / 128
  const int h = blockIdx.x & 127;
  const int w = t;
  const int lane_u = t & ~63;            // wave-uniform base for global_load_lds dest

  // zero lfb once; staging only ever writes cols [4,388), so pads persist as 0.
  for (int idx = t; idx < BATCH*3*400; idx += 128) ((float*)lfb)[idx] = 0.f;

  float acc[BATCH][OUTC];
  #pragma unroll
  for (int b = 0; b < BATCH; ++b)
    #pragma unroll
    for (int o = 0; o < OUTC; ++o) acc[b][o] = 0.f;

  for (int i = 0; i < INC; ++i) {
    #pragma unroll
    for (int o = 0; o < OUTC; ++o) {
      __syncthreads();  // previous (i,o) compute done with ldsW (also fences lfb zeroing)
      // ---- stage weight slice: 10368 contiguous floats, 16B-aligned ----
      const float* wsrc = wts + (size_t)(((s*OUTC + o)*INC + i)*OHH + h) * WSLICE;
      #pragma unroll
      for (int j = 0; j < 20; ++j)
        gll16(wsrc + (size_t)(j*128 + t)*4, ldsW + (j*128 + lane_u)*4);   // 2560 float4 chunks
      gll4(wsrc + 10240 + t, ldsW + 10240 + lane_u);                      // 128-dword tail

      for (int kc = 0; kc < 3; ++kc) {
        __syncthreads();  // previous kc compute done with lfb
        // ---- stage lf rows ky = 3kc..3kc+2 for all b (rows are 16B-aligned) ----
        const int y0 = 3*h - 3 + 3*kc;
        #pragma unroll
        for (int b = 0; b < BATCH; ++b) {
          const float* lfibase = lf + (size_t)((b*ST + s)*INC + i) * HWSZ;
          #pragma unroll
          for (int kyr = 0; kyr < 3; ++kyr) {
            const int y = y0 + kyr;
            float* drow = &lfb[b][kyr][0];
            if ((unsigned)y < (unsigned)HH) {
              const float* srow = lfibase + (size_t)y * WW;
              #pragma unroll
              for (int j = 0; j < 3; ++j)   // 384 dwords, full-wave width-4
                gll4(srow + j*128 + t, drow + 4 + j*128 + lane_u);
            } else if (t < 96) {            // out-of-bounds row -> zeros
              *reinterpret_cast<float4*>(&drow[4 + t*4]) = make_float4(0.f, 0.f, 0.f, 0.f);
            }
          }
        }
        __syncthreads();  // drains vmcnt(0): both W and lf stages landed

        // ---- compute 3 ky rows ----
        const int wb = w*KK + 3*kc*KDIM;   // ldsW base; stride-81 across lanes: conflict-free
        const int xb = 3*w + 1;            // lf col: (3w-3+kx) + 4 pad
        #pragma unroll
        for (int kyr = 0; kyr < 3; ++kyr) {
          float wr[KDIM];
          #pragma unroll
          for (int kx = 0; kx < KDIM; ++kx) wr[kx] = ldsW[wb + kyr*KDIM + kx];
          #pragma unroll
          for (int b = 0; b < BATCH; ++b) {
            const float* lrow = &lfb[b][kyr][xb];
            #pragma unroll
            for (int kx = 0; kx < KDIM; ++kx)
              acc[b][o] = fmaf(lrow[kx], wr[kx], acc[b][o]);
          }
        }
      }
    }
  }

  // ---- epilogue: bias + clip + coalesced stores ----
  #pragma unroll
  for (int o = 0; o < OUTC; ++o) {
    const float bv = bias[((s*OUTC + o)*OHH + h)*OWW + w];
    #pragma unroll
    for (int b = 0; b < BATCH; ++b) {
      float r = acc[b][o] + bv;
      r = r < 0.f ? 0.f : (r > 1.f ? 1.f : r);
      out[(((size_t)(b*ST + s)*OUTC + o)*OHH + h)*OWW + w] = r;
    }
  }
}

extern "C" void kernel_launch(void* const* d_in, const int* in_sizes, int n_in,
                              void* d_out, int out_size, void* d_ws, size_t ws_size,
                              hipStream_t stream) {
  const float* lf   = (const float*)d_in[0];
  const float* wts  = (const float*)d_in[1];
  const float* bias = (const float*)d_in[2];
  float* out = (float*)d_out;
  dim3 grid(ST * OHH);   // 1152 blocks: (s,h)
  dim3 block(128);       // thread = w
  hipLaunchKernelGGL(lf_filter_kernel, grid, block, 0, stream, lf, wts, bias, out);
}

// Round 2
// 223.191 us; speedup vs baseline: 4.0201x; 4.0201x over previous
//
#include <hip/hip_runtime.h>

// Light-field per-pixel 9x9 filter.
// out[b,s,o,h,w] = clip(sum_{i,ky,kx} lf[b,s,i,3h-3+ky,3w-3+kx] * W[s,o,i,h,w,ky*9+kx] + bias[s,o,h,w], 0, 1)
//
// Memory-bound on the 430 MB weight stream. R2 structure:
//  - block = 256 threads = (w:128) x (batch-half:2); grid = 9*128 (s,h)
//  - LDS holds ONLY the per-(s,o,i,h) weight slice (41.5 KB), staged coalesced
//    via global_load_lds width-16; read back at lane-stride 81 (conflict-free).
//  - lf read directly from global (L1/L2-resident; 12B lane stride coalesces).
//  - 3 blocks/CU (LDS-limited) x 4 waves = 12 waves/CU vs R1's 4.

#define ST 9
#define INC 3
#define OUTC 3
#define OHH 128
#define OWW 128
#define KDIM 9
#define KK 81
#define HH 384
#define WW 384
#define BATCH 4
#define HWSZ (HH*WW)          // 147456
#define WSLICE (OWW*KK)       // 10368 floats per (s,o,i,h)

__device__ __forceinline__ void gll16(const float* g, float* l) {
  __builtin_amdgcn_global_load_lds((const __attribute__((address_space(1))) void*)g,
                                   (__attribute__((address_space(3))) void*)l, 16, 0, 0);
}
__device__ __forceinline__ void gll4(const float* g, float* l) {
  __builtin_amdgcn_global_load_lds((const __attribute__((address_space(1))) void*)g,
                                   (__attribute__((address_space(3))) void*)l, 4, 0, 0);
}

__global__ __launch_bounds__(256) void lf_filter_kernel(
    const float* __restrict__ lf, const float* __restrict__ wts,
    const float* __restrict__ bias, float* __restrict__ out)
{
  __shared__ float ldsW[WSLICE];   // [w][81], 41472 B

  const int t  = threadIdx.x;
  const int w  = t & 127;          // output column
  const int bh = t >> 7;           // batch half: handles b = 2*bh, 2*bh+1
  const int s  = blockIdx.x >> 7;
  const int h  = blockIdx.x & 127;
  const int lane_u = t & ~63;      // wave-uniform LDS dest base for global_load_lds

  const int xbase = 3*w - 3;
  const int ybase = 3*h - 3;

  float acc[2][OUTC];
  #pragma unroll
  for (int bb = 0; bb < 2; ++bb)
    #pragma unroll
    for (int o = 0; o < OUTC; ++o) acc[bb][o] = 0.f;

  for (int i = 0; i < INC; ++i) {
    #pragma unroll
    for (int o = 0; o < OUTC; ++o) {
      __syncthreads();  // previous phase done reading ldsW
      // ---- stage weight slice: 10368 contiguous floats, coalesced ----
      const float* wsrc = wts + (size_t)(((s*OUTC + o)*INC + i)*OHH + h) * WSLICE;
      #pragma unroll
      for (int j = 0; j < 10; ++j)                       // 10 * 256 float4 = 10240 floats
        gll16(wsrc + (size_t)(j*256 + t)*4, ldsW + (j*256 + lane_u)*4);
      if (t < 128)                                       // 128-dword tail
        gll4(wsrc + 10240 + t, ldsW + 10240 + lane_u);
      __syncthreads();  // stage landed (barrier drains vmcnt)

      // ---- compute: 81 taps, lf straight from global ----
      const int wb = w*KK;
      const float* lfi0 = lf + (size_t)(((2*bh + 0)*ST + s)*INC + i) * HWSZ;
      const float* lfi1 = lf + (size_t)(((2*bh + 1)*ST + s)*INC + i) * HWSZ;
      #pragma unroll
      for (int ky = 0; ky < KDIM; ++ky) {
        const int y = ybase + ky;
        if ((unsigned)y < (unsigned)HH) {
          float wr[KDIM];
          #pragma unroll
          for (int kx = 0; kx < KDIM; ++kx) wr[kx] = ldsW[wb + ky*KDIM + kx];
          const float* r0 = lfi0 + (size_t)y * WW + xbase;
          const float* r1 = lfi1 + (size_t)y * WW + xbase;
          float a0 = acc[0][o], a1 = acc[1][o];
          #pragma unroll
          for (int kx = 0; kx < KDIM; ++kx) {
            const int x = xbase + kx;
            const bool ok = (unsigned)x < (unsigned)WW;
            float v0 = ok ? r0[kx] : 0.f;
            float v1 = ok ? r1[kx] : 0.f;
            a0 = fmaf(v0, wr[kx], a0);
            a1 = fmaf(v1, wr[kx], a1);
          }
          acc[0][o] = a0; acc[1][o] = a1;
        }
      }
    }
  }

  // ---- epilogue: bias + clip + coalesced stores ----
  #pragma unroll
  for (int o = 0; o < OUTC; ++o) {
    const float bv = bias[((s*OUTC + o)*OHH + h)*OWW + w];
    #pragma unroll
    for (int bb = 0; bb < 2; ++bb) {
      const int b = 2*bh + bb;
      float r = acc[bb][o] + bv;
      r = r < 0.f ? 0.f : (r > 1.f ? 1.f : r);
      out[(((size_t)(b*ST + s)*OUTC + o)*OHH + h)*OWW + w] = r;
    }
  }
}

extern "C" void kernel_launch(void* const* d_in, const int* in_sizes, int n_in,
                              void* d_out, int out_size, void* d_ws, size_t ws_size,
                              hipStream_t stream) {
  const float* lf   = (const float*)d_in[0];
  const float* wts  = (const float*)d_in[1];
  const float* bias = (const float*)d_in[2];
  float* out = (float*)d_out;
  dim3 grid(ST * OHH);   // 1152 blocks: (s,h)
  dim3 block(256);       // (w, batch-half)
  hipLaunchKernelGGL(lf_filter_kernel, grid, block, 0, stream, lf, wts, bias, out);
}